// Round 3
// baseline (434.653 us; speedup 1.0000x reference)
//
#include <hip/hip_runtime.h>
#include <math.h>

typedef _Float16 h8f16 __attribute__((ext_vector_type(8)));
typedef _Float16 h4f16 __attribute__((ext_vector_type(4)));
typedef float f32x4 __attribute__((ext_vector_type(4)));

#define MFMA16(a, b, c) __builtin_amdgcn_mfma_f32_16x16x32_f16((a), (b), (c), 0, 0, 0)

__device__ __forceinline__ float silu_f(float v) {
    return v * __builtin_amdgcn_rcpf(1.0f + __expf(-v));
}

// ---------------------------------------------------------------------------
// z0 = (past[:,0,:] @ xproj_w.T + xproj_b) @ z0_w.T + z0_b      (fp32 exact)
// ---------------------------------------------------------------------------
__global__ __launch_bounds__(128) void z0_kernel(
    const float* __restrict__ past,
    const float* __restrict__ xw, const float* __restrict__ xb,
    const float* __restrict__ zw, const float* __restrict__ zb,
    float* __restrict__ zbuf)
{
    __shared__ float p[32];
    __shared__ float x0[128];
    const int b = blockIdx.x;
    const int tid = threadIdx.x;
    if (tid < 32) p[tid] = past[(long)b * 512 * 32 + tid];
    __syncthreads();
    float s = xb[tid];
#pragma unroll
    for (int c = 0; c < 32; ++c) s += p[c] * xw[tid * 32 + c];
    x0[tid] = s;
    __syncthreads();
    float z = zb[tid];
    for (int k = 0; k < 128; ++k) z += x0[k] * zw[tid * 128 + k];
    zbuf[(long)b * 128 + tid] = z;
}

// ---------------------------------------------------------------------------
// ODE mega-kernel v3: 3 barriers/eval, swizzled LDS, LN fused into phase A.
// grid: 128 blocks (16 batch rows) x 256 threads (4 waves; wave q owns
// output columns [32q,32q+32)).
//
// Per eval:
//  A: read vS (LN input, fp32, swizzled) -> per-wave row stats via 2 shfl ->
//     LN-apply + cvt f16 A-frags -> 10 MFMA (layer1 incl. folded xproj) ->
//     silu -> h1S. barrier.
//  B: h1S -> 8 MFMA -> silu -> h2S. barrier.
//  C: h2S -> 8 MFMA -> k; RK4 bookkeeping in regs (z cached per-lane);
//     v_next = z + cin_next*k -> vS. barrier.
// ---------------------------------------------------------------------------
__global__ __launch_bounds__(256, 1) void ode_kernel(
    const float* __restrict__ past,
    const float* __restrict__ xproj_w, const float* __restrict__ xproj_b,
    const float* __restrict__ ln_g, const float* __restrict__ ln_b,
    const float* __restrict__ w1, const float* __restrict__ b1,
    const float* __restrict__ w2, const float* __restrict__ b2,
    const float* __restrict__ w3, const float* __restrict__ b3,
    float* __restrict__ zbuf)
{
    __shared__ _Float16 bxAll[65][16][40];  // 83.2 KB blended past tiles
    __shared__ float    vS[16 * 128];       // 8 KB  LN input, XOR-swizzled
    __shared__ _Float16 h1S[16 * 128];      // 4 KB  swizzled
    __shared__ _Float16 h2S[16 * 128];      // 4 KB  swizzled

    const int tid  = threadIdx.x;
    const int lane = tid & 63;
    const int wq   = tid >> 6;
    const int lrow = lane & 15;
    const int lhi  = lane >> 4;
    const int b0   = blockIdx.x * 16;
    const int rsw  = lrow & 7;              // read-side swizzle key

    // ---- weights into register B-fragments (as v2) ----
    h8f16 w1f[2][4], wcf[2], w2f[2][4], w3f[2][4];
    float b1t[2], b2r[2], b3r[2];
#pragma unroll
    for (int nt = 0; nt < 2; ++nt) {
        const int n = wq * 32 + nt * 16 + lrow;
#pragma unroll
        for (int ks = 0; ks < 4; ++ks) {
            const float* s = w1 + n * 256 + ks * 32 + lhi * 8;
            h8f16 v;
#pragma unroll
            for (int j = 0; j < 8; ++j) v[j] = (_Float16)s[j];
            w1f[nt][ks] = v;
        }
        {   // Wc = W1b @ xproj_w, bc = W1b @ xproj_b
            float wc[8] = {0, 0, 0, 0, 0, 0, 0, 0};
            float bc = 0.0f;
            const int c0 = lhi * 8;
            const float* w1b = w1 + n * 256 + 128;
#pragma unroll 4
            for (int k = 0; k < 128; ++k) {
                const float a = w1b[k];
                bc += a * xproj_b[k];
                const float* xr = xproj_w + k * 32 + c0;
#pragma unroll
                for (int j = 0; j < 8; ++j) wc[j] += a * xr[j];
            }
            h8f16 v;
#pragma unroll
            for (int j = 0; j < 8; ++j) v[j] = (_Float16)wc[j];
            wcf[nt] = v;
            b1t[nt] = b1[n] + bc;
        }
#pragma unroll
        for (int ks = 0; ks < 4; ++ks) {
            const float* s2 = w2 + n * 128 + ks * 32 + lhi * 8;
            const float* s3 = w3 + n * 128 + ks * 32 + lhi * 8;
            h8f16 v2, v3;
#pragma unroll
            for (int j = 0; j < 8; ++j) { v2[j] = (_Float16)s2[j]; v3[j] = (_Float16)s3[j]; }
            w2f[nt][ks] = v2; w3f[nt][ks] = v3;
        }
        b2r[nt] = b2[n]; b3r[nt] = b3[n];
    }

    // ln gamma/beta at this lane's A-frag columns: ks*32 + lhi*8 + j
    float gln[4][8], bln[4][8];
#pragma unroll
    for (int ks = 0; ks < 4; ++ks)
#pragma unroll
        for (int j = 0; j < 8; ++j) {
            gln[ks][j] = ln_g[ks * 32 + lhi * 8 + j];
            bln[ks][j] = ln_b[ks * 32 + lhi * 8 + j];
        }

    // ---- preload ALL 65 blended bx tiles ----
    for (int flat = tid; flat < 65 * 128; flat += 256) {
        const int e  = flat >> 7;
        const int u  = flat & 127;
        const int r  = u >> 3;
        const int c  = (u & 7) * 4;
        const float pos = (float)e * 7.984375f;
        const int i0 = (int)pos;
        const int i1 = (i0 < 511) ? i0 + 1 : 511;
        const float w = pos - (float)i0;
        const f32x4 a0 = *(const f32x4*)(past + ((long)(b0 + r) * 512 + i0) * 32 + c);
        const f32x4 a1 = *(const f32x4*)(past + ((long)(b0 + r) * 512 + i1) * 32 + c);
        h4f16 v;
#pragma unroll
        for (int j = 0; j < 4; ++j) v[j] = (_Float16)((1.0f - w) * a0[j] + w * a1[j]);
        *(h4f16*)&bxAll[e][r][c] = v;
    }

    // ---- z cached per-lane at its C-tile positions ----
    // rows 4*lhi + j (j=0..3); cols wq*32+lrow and +16
    const int cA = wq * 32 + lrow, cB = cA + 16;
    float zc[2][4];
#pragma unroll
    for (int j = 0; j < 4; ++j) {
        const long rb = (long)(b0 + 4 * lhi + j) * 128;
        zc[0][j] = zbuf[rb + cA];
        zc[1][j] = zbuf[rb + cB];
    }
    // initial vS = z  (swizzled write: blk16B ^= row&7)
#pragma unroll
    for (int j = 0; j < 4; ++j) {
        const int row = 4 * lhi + j;
        const int sA = row * 128 + (((cA >> 2) ^ (row & 7)) << 2) + (cA & 3);
        const int sB = row * 128 + (((cB >> 2) ^ (row & 7)) << 2) + (cB & 3);
        vS[sA] = zc[0][j];
        vS[sB] = zc[1][j];
    }

    f32x4 krk[2];
    krk[0] = (f32x4){0, 0, 0, 0}; krk[1] = (f32x4){0, 0, 0, 0};
    const float DT = 1.0f / 32.0f;

    __syncthreads();

#pragma unroll 1
    for (int step = 0; step < 32; ++step) {
#pragma unroll 1
        for (int sub = 0; sub < 4; ++sub) {
            const int e = 2 * step + ((sub + 1) >> 1);

            // ================= phase A: LN + layer1 =================
            {
                f32x4 va[4][2];
#pragma unroll
                for (int ks = 0; ks < 4; ++ks) {
                    const int bA = (8 * ks + 2 * lhi) ^ rsw;
                    const int bB = (8 * ks + 2 * lhi + 1) ^ rsw;
                    va[ks][0] = *(const f32x4*)&vS[lrow * 128 + (bA << 2)];
                    va[ks][1] = *(const f32x4*)&vS[lrow * 128 + (bB << 2)];
                }
                // per-wave row stats (each wave's lhi-lanes cover all 128 cols)
                float s = 0.f, q = 0.f;
#pragma unroll
                for (int ks = 0; ks < 4; ++ks)
#pragma unroll
                    for (int h = 0; h < 2; ++h)
#pragma unroll
                        for (int j = 0; j < 4; ++j) {
                            const float v = va[ks][h][j];
                            s += v; q += v * v;
                        }
                s += __shfl_xor(s, 16); q += __shfl_xor(q, 16);
                s += __shfl_xor(s, 32); q += __shfl_xor(q, 32);
                const float mu  = s * (1.0f / 128.0f);
                const float var = q * (1.0f / 128.0f) - mu * mu;
                const float inv = 1.0f / sqrtf(var + 1e-5f);

                h8f16 az[4];
#pragma unroll
                for (int ks = 0; ks < 4; ++ks) {
                    h8f16 o;
#pragma unroll
                    for (int j = 0; j < 8; ++j) {
                        const float v = va[ks][j >> 2][j & 3];
                        o[j] = (_Float16)((v - mu) * inv * gln[ks][j] + bln[ks][j]);
                    }
                    az[ks] = o;
                }
                const h8f16 bx = *(const h8f16*)&bxAll[e][lrow][lhi * 8];
                f32x4 a0 = {0, 0, 0, 0}, a1 = {0, 0, 0, 0};
#pragma unroll
                for (int ks = 0; ks < 4; ++ks) {
                    a0 = MFMA16(az[ks], w1f[0][ks], a0);
                    a1 = MFMA16(az[ks], w1f[1][ks], a1);
                }
                a0 = MFMA16(bx, wcf[0], a0);
                a1 = MFMA16(bx, wcf[1], a1);
#pragma unroll
                for (int j = 0; j < 4; ++j) {
                    const int row = 4 * lhi + j;
                    const int pA = row * 128 + ((((cA >> 3) ^ (row & 7)) << 3)) + (cA & 7);
                    const int pB = row * 128 + ((((cB >> 3) ^ (row & 7)) << 3)) + (cB & 7);
                    h1S[pA] = (_Float16)silu_f(a0[j] + b1t[0]);
                    h1S[pB] = (_Float16)silu_f(a1[j] + b1t[1]);
                }
            }
            __syncthreads();

            // ================= phase B: layer2 =================
            {
                f32x4 a0 = {0, 0, 0, 0}, a1 = {0, 0, 0, 0};
#pragma unroll
                for (int ks = 0; ks < 4; ++ks) {
                    const int blk = (4 * ks + lhi) ^ rsw;
                    h8f16 a = *(const h8f16*)&h1S[lrow * 128 + (blk << 3)];
                    a0 = MFMA16(a, w2f[0][ks], a0);
                    a1 = MFMA16(a, w2f[1][ks], a1);
                }
#pragma unroll
                for (int j = 0; j < 4; ++j) {
                    const int row = 4 * lhi + j;
                    const int pA = row * 128 + ((((cA >> 3) ^ (row & 7)) << 3)) + (cA & 7);
                    const int pB = row * 128 + ((((cB >> 3) ^ (row & 7)) << 3)) + (cB & 7);
                    h2S[pA] = (_Float16)silu_f(a0[j] + b2r[0]);
                    h2S[pB] = (_Float16)silu_f(a1[j] + b2r[1]);
                }
            }
            __syncthreads();

            // ================= phase C: layer3 + RK4 + v_next =================
            {
                f32x4 a0 = {0, 0, 0, 0}, a1 = {0, 0, 0, 0};
#pragma unroll
                for (int ks = 0; ks < 4; ++ks) {
                    const int blk = (4 * ks + lhi) ^ rsw;
                    h8f16 a = *(const h8f16*)&h2S[lrow * 128 + (blk << 3)];
                    a0 = MFMA16(a, w3f[0][ks], a0);
                    a1 = MFMA16(a, w3f[1][ks], a1);
                }
#pragma unroll
                for (int j = 0; j < 4; ++j) {
                    const float k0v = a0[j] + b3r[0];
                    const float k1v = a1[j] + b3r[1];
                    float v0, v1;
                    if (sub == 0) {
                        krk[0][j] = k0v; krk[1][j] = k1v;
                        v0 = zc[0][j] + 0.5f * DT * k0v;
                        v1 = zc[1][j] + 0.5f * DT * k1v;
                    } else if (sub == 1) {
                        krk[0][j] += 2.0f * k0v; krk[1][j] += 2.0f * k1v;
                        v0 = zc[0][j] + 0.5f * DT * k0v;
                        v1 = zc[1][j] + 0.5f * DT * k1v;
                    } else if (sub == 2) {
                        krk[0][j] += 2.0f * k0v; krk[1][j] += 2.0f * k1v;
                        v0 = zc[0][j] + DT * k0v;
                        v1 = zc[1][j] + DT * k1v;
                    } else {
                        zc[0][j] += (DT / 6.0f) * (krk[0][j] + k0v);
                        zc[1][j] += (DT / 6.0f) * (krk[1][j] + k1v);
                        v0 = zc[0][j];
                        v1 = zc[1][j];
                    }
                    const int row = 4 * lhi + j;
                    const int sA = row * 128 + (((cA >> 2) ^ (row & 7)) << 2) + (cA & 3);
                    const int sB = row * 128 + (((cB >> 2) ^ (row & 7)) << 2) + (cB & 3);
                    vS[sA] = v0;
                    vS[sB] = v1;
                }
            }
            __syncthreads();
        }
    }

    // ---- store final z ----
#pragma unroll
    for (int j = 0; j < 4; ++j) {
        const long rb = (long)(b0 + 4 * lhi + j) * 128;
        zbuf[rb + cA] = zc[0][j];
        zbuf[rb + cB] = zc[1][j];
    }
}

// ---------------------------------------------------------------------------
// cbuf = [cond (128) | time-emb (128)] as f16, per batch row (1 MB)
// ---------------------------------------------------------------------------
__global__ __launch_bounds__(256) void cbuf_kernel(
    const float* __restrict__ cond, const int* __restrict__ tvals,
    _Float16* __restrict__ cbuf)
{
    const int gid = blockIdx.x * 256 + threadIdx.x;
    const int b  = gid >> 5;
    const int j0 = (gid & 31) * 8;
    h8f16 v;
    if (j0 < 128) {
        const float* s = cond + (long)b * 128 + j0;
#pragma unroll
        for (int j = 0; j < 8; ++j) v[j] = (_Float16)s[j];
    } else {
        const float tv = (float)tvals[b];
#pragma unroll
        for (int j = 0; j < 8; ++j) {
            const int jj  = j0 - 128 + j;
            const int idx = (jj < 64) ? jj : jj - 64;
            const float fr = expf(-9.210340371976184f * (float)idx * (1.0f / 63.0f));
            const float a  = tv * fr;
            v[j] = (_Float16)((jj < 64) ? sinf(a) : cosf(a));
        }
    }
    *(h8f16*)&cbuf[(long)b * 256 + j0] = v;
}

// ---------------------------------------------------------------------------
// gemm1: h1 = silu([x_t | cbuf] @ fw1.T + fb1)   M=2048 N=256 K=3328
// A staged from x_t (f32, k<3072) or cbuf (f16, k>=3072).
// ---------------------------------------------------------------------------
__global__ __launch_bounds__(256) void gemm1_kernel(
    const float* __restrict__ x_t, const _Float16* __restrict__ cbuf,
    const float* __restrict__ W, const float* __restrict__ bias,
    _Float16* __restrict__ out)
{
    const int M = 2048, N = 256, K = 3328;
    __shared__ _Float16 aS[64][40];
    __shared__ _Float16 wS[64][40];
    const int mb = blockIdx.x * 64, nb = blockIdx.y * 64;
    const int tid = threadIdx.x, lane = tid & 63, wq = tid >> 6;
    const int lrow = lane & 15, lhi = lane >> 4;
    f32x4 acc[4];
#pragma unroll
    for (int nt = 0; nt < 4; ++nt) acc[nt] = (f32x4){0, 0, 0, 0};

    const int sr = tid >> 2;
    const int sk = (tid & 3) * 8;

    for (int k0 = 0; k0 < K; k0 += 32) {
        if (k0 < 3072) {
            const float* s = x_t + (long)(mb + sr) * 3072 + k0 + sk;
            h8f16 v;
#pragma unroll
            for (int j = 0; j < 8; ++j) v[j] = (_Float16)s[j];
            *(h8f16*)&aS[sr][sk] = v;
        } else {
            *(h8f16*)&aS[sr][sk] =
                *(const h8f16*)&cbuf[(long)(mb + sr) * 256 + (k0 - 3072) + sk];
        }
        {
            const float* s = &W[(long)(nb + sr) * K + k0 + sk];
            h8f16 v;
#pragma unroll
            for (int j = 0; j < 8; ++j) v[j] = (_Float16)s[j];
            *(h8f16*)&wS[sr][sk] = v;
        }
        __syncthreads();
        h8f16 a = *(const h8f16*)&aS[wq * 16 + lrow][lhi * 8];
#pragma unroll
        for (int nt = 0; nt < 4; ++nt) {
            h8f16 bfr = *(const h8f16*)&wS[nt * 16 + lrow][lhi * 8];
            acc[nt] = MFMA16(a, bfr, acc[nt]);
        }
        __syncthreads();
    }

#pragma unroll
    for (int nt = 0; nt < 4; ++nt) {
        const int cc = nb + nt * 16 + lrow;
        const float bv = bias[cc];
#pragma unroll
        for (int j = 0; j < 4; ++j) {
            const int rr = mb + wq * 16 + lhi * 4 + j;
            out[(long)rr * N + cc] = (_Float16)silu_f(acc[nt][j] + bv);
        }
    }
}

// ---------------------------------------------------------------------------
// Generic f16-MFMA GEMM: out(M,N) = [silu](A(M,K) @ W(N,K).T + bias)
// ---------------------------------------------------------------------------
template <bool SILU, bool OUT_F16>
__global__ __launch_bounds__(256) void gemm_f16(
    const _Float16* __restrict__ A, const float* __restrict__ W,
    const float* __restrict__ bias, void* __restrict__ out,
    int M, int N, int K)
{
    __shared__ _Float16 aS[64][40];
    __shared__ _Float16 wS[64][40];
    const int mb = blockIdx.x * 64, nb = blockIdx.y * 64;
    const int tid = threadIdx.x, lane = tid & 63, wq = tid >> 6;
    const int lrow = lane & 15, lhi = lane >> 4;
    f32x4 acc[4];
#pragma unroll
    for (int nt = 0; nt < 4; ++nt) acc[nt] = (f32x4){0, 0, 0, 0};

    const int sr = tid >> 2;
    const int sk = (tid & 3) * 8;

    for (int k0 = 0; k0 < K; k0 += 32) {
        {
            h8f16 v = *(const h8f16*)&A[(long)(mb + sr) * K + k0 + sk];
            *(h8f16*)&aS[sr][sk] = v;
        }
        {
            const float* s = &W[(long)(nb + sr) * K + k0 + sk];
            h8f16 v;
#pragma unroll
            for (int j = 0; j < 8; ++j) v[j] = (_Float16)s[j];
            *(h8f16*)&wS[sr][sk] = v;
        }
        __syncthreads();
        h8f16 a = *(const h8f16*)&aS[wq * 16 + lrow][lhi * 8];
#pragma unroll
        for (int nt = 0; nt < 4; ++nt) {
            h8f16 bfr = *(const h8f16*)&wS[nt * 16 + lrow][lhi * 8];
            acc[nt] = MFMA16(a, bfr, acc[nt]);
        }
        __syncthreads();
    }

#pragma unroll
    for (int nt = 0; nt < 4; ++nt) {
        const int cc = nb + nt * 16 + lrow;
        const float bv = bias[cc];
#pragma unroll
        for (int j = 0; j < 4; ++j) {
            const int rr = mb + wq * 16 + lhi * 4 + j;
            float v = acc[nt][j] + bv;
            if (SILU) v = silu_f(v);
            if (OUT_F16) ((_Float16*)out)[(long)rr * N + cc] = (_Float16)v;
            else         ((float*)out)[(long)rr * N + cc] = v;
        }
    }
}

// ---------------------------------------------------------------------------
extern "C" void kernel_launch(void* const* d_in, const int* in_sizes, int n_in,
                              void* d_out, int out_size, void* d_ws, size_t ws_size,
                              hipStream_t stream)
{
    const float* x_t     = (const float*)d_in[0];
    const float* past    = (const float*)d_in[1];
    const int*   tvals   = (const int*)d_in[2];
    const float* xproj_w = (const float*)d_in[3];
    const float* xproj_b = (const float*)d_in[4];
    const float* z0_w    = (const float*)d_in[5];
    const float* z0_b    = (const float*)d_in[6];
    const float* ln_g    = (const float*)d_in[7];
    const float* ln_b    = (const float*)d_in[8];
    const float* w1      = (const float*)d_in[9];
    const float* b1      = (const float*)d_in[10];
    const float* w2      = (const float*)d_in[11];
    const float* b2      = (const float*)d_in[12];
    const float* w3      = (const float*)d_in[13];
    const float* b3      = (const float*)d_in[14];
    const float* fw1     = (const float*)d_in[15];
    const float* fb1     = (const float*)d_in[16];
    const float* fw2     = (const float*)d_in[17];
    const float* fb2     = (const float*)d_in[18];
    const float* fw3     = (const float*)d_in[19];
    const float* fb3     = (const float*)d_in[20];

    char* ws = (char*)d_ws;
    float*     zbuf = (float*)ws;                       // 1 MB
    _Float16*  cbuf = (_Float16*)(ws + (1 << 20));      // 1 MB
    _Float16*  h1   = (_Float16*)(ws + 2 * (1 << 20));  // 1 MB
    _Float16*  h2   = (_Float16*)(ws + 3 * (1 << 20));  // 1 MB

    z0_kernel<<<2048, 128, 0, stream>>>(past, xproj_w, xproj_b, z0_w, z0_b, zbuf);

    ode_kernel<<<128, 256, 0, stream>>>(past, xproj_w, xproj_b, ln_g, ln_b,
                                        w1, b1, w2, b2, w3, b3, zbuf);

    cbuf_kernel<<<256, 256, 0, stream>>>(zbuf, tvals, cbuf);

    gemm1_kernel<<<dim3(32, 4), 256, 0, stream>>>(x_t, cbuf, fw1, fb1, h1);
    gemm_f16<true,  true ><<<dim3(32, 4),  256, 0, stream>>>(h1, fw2, fb2, h2, 2048, 256, 256);
    gemm_f16<false, false><<<dim3(32, 48), 256, 0, stream>>>(h2, fw3, fb3, d_out, 2048, 3072, 256);
}

// Round 5
// 372.324 us; speedup vs baseline: 1.1674x; 1.1674x over previous
//
#include <hip/hip_runtime.h>
#include <math.h>

typedef _Float16 h8f16 __attribute__((ext_vector_type(8)));
typedef float f32x4 __attribute__((ext_vector_type(4)));

#define MFMA16(a, b, c) __builtin_amdgcn_mfma_f32_16x16x32_f16((a), (b), (c), 0, 0, 0)

__device__ __forceinline__ float silu_f(float v) {
    return v * __builtin_amdgcn_rcpf(1.0f + __expf(-v));
}

// ---------------------------------------------------------------------------
// ODE mega-kernel v5.
// grid: 128 blocks (16 batch rows) x 512 threads (8 waves; wave w owns output
// cols [16w, 16w+16) of every layer -> 2 waves/SIMD for latency hiding).
//  - z0 computed in-kernel (exact f32, LDS staged).
//  - LN gamma folded into W1a cols, beta folded into b1 (exact algebra);
//    LN apply = x*inv + (-mu*inv) in packed f16.
//  - Per-row LN stats per wave (v3 proven scheme): each wave's A-frag lanes
//    cover all 128 cols of a row; in-lane f32 sums + shfl_xor(16,32).
//  - bx (lerped past row, K=32) streamed per-lane from global into registers
//    with a 3-barrier prefetch lead; no bxAll LDS.
// ---------------------------------------------------------------------------
__global__ __launch_bounds__(512, 1) void ode_kernel(
    const float* __restrict__ past,
    const float* __restrict__ xproj_w, const float* __restrict__ xproj_b,
    const float* __restrict__ z0_w, const float* __restrict__ z0_b,
    const float* __restrict__ ln_g, const float* __restrict__ ln_b,
    const float* __restrict__ w1, const float* __restrict__ b1,
    const float* __restrict__ w2, const float* __restrict__ b2,
    const float* __restrict__ w3, const float* __restrict__ b3,
    float* __restrict__ zbuf)
{
    __shared__ _Float16 hbuf[16][136];   // LN input v
    __shared__ _Float16 h1S[16][136];
    __shared__ _Float16 h2S[16][136];
    __shared__ float    pS[16][33];      // past[:,0,:] stage (prologue)
    __shared__ float    x0S[16][128];    // x_seq[:,0,:] (prologue)
    __shared__ float    zS0[16][129];    // z0 (prologue)

    const int tid  = threadIdx.x;
    const int wid  = tid >> 6;
    const int lane = tid & 63;
    const int lrow = lane & 15;
    const int lhi  = lane >> 4;
    const int b0   = blockIdx.x * 16;
    const int nc   = wid * 16 + lrow;    // this lane's output col (all layers)
    const int koff = lhi * 8;

    // ---- weights into register B-fragments; gamma folded into W1a ----
    h8f16 w1f[4], wcf, w2f[4], w3f[4];
    float b1t, b2r, b3r;
    {
#pragma unroll
        for (int ks = 0; ks < 4; ++ks) {
            h8f16 v1, v2, v3;
#pragma unroll
            for (int j = 0; j < 8; ++j) {
                const int k = ks * 32 + koff + j;
                v1[j] = (_Float16)(w1[nc * 256 + k] * ln_g[k]);
                v2[j] = (_Float16)w2[nc * 128 + k];
                v3[j] = (_Float16)w3[nc * 128 + k];
            }
            w1f[ks] = v1; w2f[ks] = v2; w3f[ks] = v3;
        }
        // Wc = W1b @ xproj_w ; bc = W1b @ xproj_b ; bb = W1a @ ln_b
        float wc[8] = {0, 0, 0, 0, 0, 0, 0, 0};
        float bc = 0.0f, bb = 0.0f;
        const float* w1a = w1 + nc * 256;
        const float* w1b = w1a + 128;
#pragma unroll 4
        for (int k = 0; k < 128; ++k) {
            const float a = w1b[k];
            bc += a * xproj_b[k];
            bb += w1a[k] * ln_b[k];
            const float* xr = xproj_w + k * 32 + koff;
#pragma unroll
            for (int j = 0; j < 8; ++j) wc[j] += a * xr[j];
        }
        h8f16 v;
#pragma unroll
        for (int j = 0; j < 8; ++j) v[j] = (_Float16)wc[j];
        wcf = v;
        b1t = b1[nc] + bc + bb;
        b2r = b2[nc]; b3r = b3[nc];
    }

    // ---- prologue: z0 = (past[:,0,:] @ xw.T + xb) @ z0w.T + z0b (f32) ----
    pS[tid >> 5][tid & 31] = past[(long)(b0 + (tid >> 5)) * 16384 + (tid & 31)];
    __syncthreads();
    {
        const int r  = tid >> 5;
        const int c0 = (tid & 31) * 4;
#pragma unroll
        for (int cc = 0; cc < 4; ++cc) {
            const int kc = c0 + cc;
            float s = xproj_b[kc];
            const float* xr = xproj_w + kc * 32;
#pragma unroll
            for (int c = 0; c < 32; ++c) s += pS[r][c] * xr[c];
            x0S[r][kc] = s;
        }
    }
    __syncthreads();
    {
        const int nn = tid & 127;
        const int r0 = (tid >> 7) * 4;
        for (int p = 0; p < 4; ++p) {
            const int r = r0 + p;
            float s = z0_b[nn];
            const float* zr = z0_w + nn * 128;
            for (int k = 0; k < 128; ++k) s += x0S[r][k] * zr[k];
            zS0[r][nn] = s;
        }
    }
    __syncthreads();

    // ---- z cached per-lane in C-frag layout (rows 4*lhi+j, col nc) ----
    float zc[4], krk[4];
#pragma unroll
    for (int j = 0; j < 4; ++j) {
        zc[j] = zS0[4 * lhi + j][nc];
        hbuf[4 * lhi + j][nc] = (_Float16)zc[j];
    }

    const float DT = 1.0f / 32.0f;

    // ---- bx streaming machinery ----
    f32x4 s0a, s0b, s1a, s1b;
    auto stage = [&](int e) {
        const float pos = (float)e * 7.984375f;   // e*(511/64), exact
        const int i0 = (int)pos;
        const int i1 = (i0 < 511) ? i0 + 1 : 511;
        const float* base = past + (long)(b0 + lrow) * 16384;
        const float* p0 = base + i0 * 32 + koff;
        const float* p1 = base + i1 * 32 + koff;
        s0a = *(const f32x4*)p0; s0b = *(const f32x4*)(p0 + 4);
        s1a = *(const f32x4*)p1; s1b = *(const f32x4*)(p1 + 4);
    };
    auto blend = [&](int e) -> h8f16 {
        const float pos = (float)e * 7.984375f;
        const float w = pos - floorf(pos);
        h8f16 r;
#pragma unroll
        for (int j = 0; j < 4; ++j) {
            r[j]     = (_Float16)(s0a[j] + w * (s1a[j] - s0a[j]));
            r[4 + j] = (_Float16)(s0b[j] + w * (s1b[j] - s0b[j]));
        }
        return r;
    };

    // ---- phases ----
    auto phaseA = [&](h8f16 bxc) {
        h8f16 xf[4];
#pragma unroll
        for (int ks = 0; ks < 4; ++ks)
            xf[ks] = *(const h8f16*)&hbuf[lrow][ks * 32 + koff];
        float s = 0.f, q = 0.f;
#pragma unroll
        for (int ks = 0; ks < 4; ++ks)
#pragma unroll
            for (int j = 0; j < 8; ++j) {
                const float v = (float)xf[ks][j];
                s += v; q = fmaf(v, v, q);
            }
        s += __shfl_xor(s, 16); q += __shfl_xor(q, 16);
        s += __shfl_xor(s, 32); q += __shfl_xor(q, 32);
        const float mu  = s * (1.0f / 128.0f);
        const float var = q * (1.0f / 128.0f) - mu * mu;
        const float inv = 1.0f / sqrtf(var + 1e-5f);
        const _Float16 ih = (_Float16)inv;
        const _Float16 mh = (_Float16)(-mu * inv);
        h8f16 ip, mp;
#pragma unroll
        for (int j = 0; j < 8; ++j) { ip[j] = ih; mp[j] = mh; }
        f32x4 acc = {0, 0, 0, 0};
#pragma unroll
        for (int ks = 0; ks < 4; ++ks) {
            const h8f16 az = xf[ks] * ip + mp;   // packed f16 LN-apply
            acc = MFMA16(az, w1f[ks], acc);
        }
        acc = MFMA16(bxc, wcf, acc);
#pragma unroll
        for (int j = 0; j < 4; ++j)
            h1S[4 * lhi + j][nc] = (_Float16)silu_f(acc[j] + b1t);
    };
    auto phaseB = [&]() {
        f32x4 acc = {0, 0, 0, 0};
#pragma unroll
        for (int ks = 0; ks < 4; ++ks) {
            const h8f16 a = *(const h8f16*)&h1S[lrow][ks * 32 + koff];
            acc = MFMA16(a, w2f[ks], acc);
        }
#pragma unroll
        for (int j = 0; j < 4; ++j)
            h2S[4 * lhi + j][nc] = (_Float16)silu_f(acc[j] + b2r);
    };
    auto phaseC = [&]() -> f32x4 {
        f32x4 acc = {0, 0, 0, 0};
#pragma unroll
        for (int ks = 0; ks < 4; ++ks) {
            const h8f16 a = *(const h8f16*)&h2S[lrow][ks * 32 + koff];
            acc = MFMA16(a, w3f[ks], acc);
        }
#pragma unroll
        for (int j = 0; j < 4; ++j) acc[j] += b3r;
        return acc;
    };

    stage(0);
    h8f16 bxc = blend(0);
    __syncthreads();

#pragma unroll 1
    for (int st = 0; st < 32; ++st) {
        const int e1 = 2 * st + 1, e2 = 2 * st + 2;
        // ---- sub0: k1 ----
        phaseA(bxc);
        stage(e1);                                   // prefetch tile e1
        __syncthreads();
        phaseB(); __syncthreads();
        {
            const f32x4 k = phaseC();
#pragma unroll
            for (int j = 0; j < 4; ++j) {
                krk[j] = k[j];
                hbuf[4 * lhi + j][nc] = (_Float16)(zc[j] + 0.5f * DT * k[j]);
            }
        }
        __syncthreads();
        // ---- sub1: k2 ----
        bxc = blend(e1);
        phaseA(bxc); __syncthreads();
        phaseB(); __syncthreads();
        {
            const f32x4 k = phaseC();
#pragma unroll
            for (int j = 0; j < 4; ++j) {
                krk[j] += 2.0f * k[j];
                hbuf[4 * lhi + j][nc] = (_Float16)(zc[j] + 0.5f * DT * k[j]);
            }
        }
        __syncthreads();
        // ---- sub2: k3 ----
        phaseA(bxc);
        stage(e2);                                   // prefetch tile e2
        __syncthreads();
        phaseB(); __syncthreads();
        {
            const f32x4 k = phaseC();
#pragma unroll
            for (int j = 0; j < 4; ++j) {
                krk[j] += 2.0f * k[j];
                hbuf[4 * lhi + j][nc] = (_Float16)(zc[j] + DT * k[j]);
            }
        }
        __syncthreads();
        // ---- sub3: k4 + z update ----
        bxc = blend(e2);
        phaseA(bxc); __syncthreads();
        phaseB(); __syncthreads();
        {
            const f32x4 k = phaseC();
#pragma unroll
            for (int j = 0; j < 4; ++j) {
                zc[j] += (DT / 6.0f) * (krk[j] + k[j]);
                hbuf[4 * lhi + j][nc] = (_Float16)zc[j];
            }
        }
        __syncthreads();
    }

#pragma unroll
    for (int j = 0; j < 4; ++j)
        zbuf[(long)(b0 + 4 * lhi + j) * 128 + nc] = zc[j];
}

// ---------------------------------------------------------------------------
// hcat = [x_t flat (3072) | cond (128) | time-emb (128)] as f16
// ---------------------------------------------------------------------------
__global__ __launch_bounds__(256) void hcat_kernel(
    const float* __restrict__ x_t, const float* __restrict__ cond,
    const int* __restrict__ tvals, _Float16* __restrict__ hcat)
{
    const int gid = blockIdx.x * 256 + threadIdx.x;
    const int b  = gid / 416;
    const int j0 = (gid % 416) * 8;
    h8f16 v;
    if (j0 < 3072) {
        const float* s = x_t + (long)b * 3072 + j0;
#pragma unroll
        for (int j = 0; j < 8; ++j) v[j] = (_Float16)s[j];
    } else if (j0 < 3200) {
        const float* s = cond + (long)b * 128 + (j0 - 3072);
#pragma unroll
        for (int j = 0; j < 8; ++j) v[j] = (_Float16)s[j];
    } else {
        const float tv = (float)tvals[b];
#pragma unroll
        for (int j = 0; j < 8; ++j) {
            const int jj  = j0 - 3200 + j;
            const int idx = (jj < 64) ? jj : jj - 64;
            const float fr = expf(-9.210340371976184f * (float)idx * (1.0f / 63.0f));
            const float a  = tv * fr;
            v[j] = (_Float16)((jj < 64) ? sinf(a) : cosf(a));
        }
    }
    *(h8f16*)&hcat[(long)b * 3328 + j0] = v;
}

// ---------------------------------------------------------------------------
// Generic f16-MFMA GEMM: out(M,N) = [silu](A(M,K) @ W(N,K).T + bias)
// ---------------------------------------------------------------------------
template <bool SILU, bool OUT_F16>
__global__ __launch_bounds__(256) void gemm_f16(
    const _Float16* __restrict__ A, const float* __restrict__ W,
    const float* __restrict__ bias, void* __restrict__ out,
    int M, int N, int K)
{
    __shared__ _Float16 aS[64][40];
    __shared__ _Float16 wS[64][40];
    const int mb = blockIdx.x * 64, nb = blockIdx.y * 64;
    const int tid = threadIdx.x, lane = tid & 63, wq = tid >> 6;
    const int lrow = lane & 15, lhi = lane >> 4;
    f32x4 acc[4];
#pragma unroll
    for (int nt = 0; nt < 4; ++nt) acc[nt] = (f32x4){0, 0, 0, 0};

    const int sr = tid >> 2;
    const int sk = (tid & 3) * 8;

    for (int k0 = 0; k0 < K; k0 += 32) {
        {
            h8f16 v = *(const h8f16*)&A[(long)(mb + sr) * K + k0 + sk];
            *(h8f16*)&aS[sr][sk] = v;
        }
        {
            const float* s = &W[(long)(nb + sr) * K + k0 + sk];
            h8f16 v;
#pragma unroll
            for (int j = 0; j < 8; ++j) v[j] = (_Float16)s[j];
            *(h8f16*)&wS[sr][sk] = v;
        }
        __syncthreads();
        h8f16 a = *(const h8f16*)&aS[wq * 16 + lrow][lhi * 8];
#pragma unroll
        for (int nt = 0; nt < 4; ++nt) {
            h8f16 bfr = *(const h8f16*)&wS[nt * 16 + lrow][lhi * 8];
            acc[nt] = MFMA16(a, bfr, acc[nt]);
        }
        __syncthreads();
    }

#pragma unroll
    for (int nt = 0; nt < 4; ++nt) {
        const int cc = nb + nt * 16 + lrow;
        const float bv = bias[cc];
#pragma unroll
        for (int j = 0; j < 4; ++j) {
            const int rr = mb + wq * 16 + lhi * 4 + j;
            float v = acc[nt][j] + bv;
            if (SILU) v = silu_f(v);
            if (OUT_F16) ((_Float16*)out)[(long)rr * N + cc] = (_Float16)v;
            else         ((float*)out)[(long)rr * N + cc] = v;
        }
    }
}

// ---------------------------------------------------------------------------
extern "C" void kernel_launch(void* const* d_in, const int* in_sizes, int n_in,
                              void* d_out, int out_size, void* d_ws, size_t ws_size,
                              hipStream_t stream)
{
    const float* x_t     = (const float*)d_in[0];
    const float* past    = (const float*)d_in[1];
    const int*   tvals   = (const int*)d_in[2];
    const float* xproj_w = (const float*)d_in[3];
    const float* xproj_b = (const float*)d_in[4];
    const float* z0_w    = (const float*)d_in[5];
    const float* z0_b    = (const float*)d_in[6];
    const float* ln_g    = (const float*)d_in[7];
    const float* ln_b    = (const float*)d_in[8];
    const float* w1      = (const float*)d_in[9];
    const float* b1      = (const float*)d_in[10];
    const float* w2      = (const float*)d_in[11];
    const float* b2      = (const float*)d_in[12];
    const float* w3      = (const float*)d_in[13];
    const float* b3      = (const float*)d_in[14];
    const float* fw1     = (const float*)d_in[15];
    const float* fb1     = (const float*)d_in[16];
    const float* fw2     = (const float*)d_in[17];
    const float* fb2     = (const float*)d_in[18];
    const float* fw3     = (const float*)d_in[19];
    const float* fb3     = (const float*)d_in[20];

    char* ws = (char*)d_ws;
    float*     zbuf = (float*)ws;                               // 1 MB
    _Float16*  hcat = (_Float16*)(ws + (1 << 20));              // 13.63 MB
    _Float16*  h1   = (_Float16*)(ws + 15 * (1 << 20));         // 1 MB
    _Float16*  h2   = (_Float16*)(ws + 16 * (1 << 20));         // 1 MB

    ode_kernel<<<128, 512, 0, stream>>>(past, xproj_w, xproj_b, z0_w, z0_b,
                                        ln_g, ln_b, w1, b1, w2, b2, w3, b3, zbuf);

    hcat_kernel<<<(2048 * 416) / 256, 256, 0, stream>>>(x_t, zbuf, tvals, hcat);

    gemm_f16<true,  true ><<<dim3(32, 4),  256, 0, stream>>>(hcat, fw1, fb1, h1, 2048, 256, 3328);
    gemm_f16<true,  true ><<<dim3(32, 4),  256, 0, stream>>>(h1,   fw2, fb2, h2, 2048, 256, 256);
    gemm_f16<false, false><<<dim3(32, 48), 256, 0, stream>>>(h2,   fw3, fb3, d_out, 2048, 3072, 256);
}

// Round 6
// 324.326 us; speedup vs baseline: 1.3402x; 1.1480x over previous
//
#include <hip/hip_runtime.h>
#include <math.h>

typedef _Float16 h8f16 __attribute__((ext_vector_type(8)));
typedef _Float16 h2f16 __attribute__((ext_vector_type(2)));
typedef float f32x4 __attribute__((ext_vector_type(4)));

#define MFMA16(a, b, c) __builtin_amdgcn_mfma_f32_16x16x32_f16((a), (b), (c), 0, 0, 0)

__device__ __forceinline__ float silu_f(float v) {
    return v * __builtin_amdgcn_rcpf(1.0f + __expf(-v));
}

// Bare barrier: writer-side LDS completion + s_barrier, NO vmcnt drain.
// (HK 8-phase pattern: global loads stay in flight across barriers.)
__device__ __forceinline__ void bar_lds() {
    asm volatile("s_waitcnt lgkmcnt(0)" ::: "memory");
    __builtin_amdgcn_s_barrier();
    __builtin_amdgcn_sched_barrier(0);
}

// ---------------------------------------------------------------------------
// ODE mega-kernel v6 = v5 + bare barriers (no vmcnt drain in loop)
//                    + fdot2-based LN stats.
// grid: 128 blocks (16 batch rows) x 512 threads (8 waves; wave w owns output
// cols [16w, 16w+16)).
// ---------------------------------------------------------------------------
__global__ __launch_bounds__(512, 1) void ode_kernel(
    const float* __restrict__ past,
    const float* __restrict__ xproj_w, const float* __restrict__ xproj_b,
    const float* __restrict__ z0_w, const float* __restrict__ z0_b,
    const float* __restrict__ ln_g, const float* __restrict__ ln_b,
    const float* __restrict__ w1, const float* __restrict__ b1,
    const float* __restrict__ w2, const float* __restrict__ b2,
    const float* __restrict__ w3, const float* __restrict__ b3,
    float* __restrict__ zbuf)
{
    __shared__ _Float16 hbuf[16][136];   // LN input v
    __shared__ _Float16 h1S[16][136];
    __shared__ _Float16 h2S[16][136];
    __shared__ float    pS[16][33];      // prologue stages
    __shared__ float    x0S[16][128];
    __shared__ float    zS0[16][129];

    const int tid  = threadIdx.x;
    const int wid  = tid >> 6;
    const int lane = tid & 63;
    const int lrow = lane & 15;
    const int lhi  = lane >> 4;
    const int b0   = blockIdx.x * 16;
    const int nc   = wid * 16 + lrow;    // this lane's output col (all layers)
    const int koff = lhi * 8;

    // ---- weights into register B-fragments; gamma folded into W1a ----
    h8f16 w1f[4], wcf, w2f[4], w3f[4];
    float b1t, b2r, b3r;
    {
#pragma unroll
        for (int ks = 0; ks < 4; ++ks) {
            h8f16 v1, v2, v3;
#pragma unroll
            for (int j = 0; j < 8; ++j) {
                const int k = ks * 32 + koff + j;
                v1[j] = (_Float16)(w1[nc * 256 + k] * ln_g[k]);
                v2[j] = (_Float16)w2[nc * 128 + k];
                v3[j] = (_Float16)w3[nc * 128 + k];
            }
            w1f[ks] = v1; w2f[ks] = v2; w3f[ks] = v3;
        }
        // Wc = W1b @ xproj_w ; bc = W1b @ xproj_b ; bb = W1a @ ln_b
        float wc[8] = {0, 0, 0, 0, 0, 0, 0, 0};
        float bc = 0.0f, bb = 0.0f;
        const float* w1a = w1 + nc * 256;
        const float* w1b = w1a + 128;
#pragma unroll 4
        for (int k = 0; k < 128; ++k) {
            const float a = w1b[k];
            bc += a * xproj_b[k];
            bb += w1a[k] * ln_b[k];
            const float* xr = xproj_w + k * 32 + koff;
#pragma unroll
            for (int j = 0; j < 8; ++j) wc[j] += a * xr[j];
        }
        h8f16 v;
#pragma unroll
        for (int j = 0; j < 8; ++j) v[j] = (_Float16)wc[j];
        wcf = v;
        b1t = b1[nc] + bc + bb;
        b2r = b2[nc]; b3r = b3[nc];
    }

    // ---- prologue: z0 = (past[:,0,:] @ xw.T + xb) @ z0w.T + z0b (f32) ----
    pS[tid >> 5][tid & 31] = past[(long)(b0 + (tid >> 5)) * 16384 + (tid & 31)];
    __syncthreads();
    {
        const int r  = tid >> 5;
        const int c0 = (tid & 31) * 4;
#pragma unroll
        for (int cc = 0; cc < 4; ++cc) {
            const int kc = c0 + cc;
            float s = xproj_b[kc];
            const float* xr = xproj_w + kc * 32;
#pragma unroll
            for (int c = 0; c < 32; ++c) s += pS[r][c] * xr[c];
            x0S[r][kc] = s;
        }
    }
    __syncthreads();
    {
        const int nn = tid & 127;
        const int r0 = (tid >> 7) * 4;
        for (int p = 0; p < 4; ++p) {
            const int r = r0 + p;
            float s = z0_b[nn];
            const float* zr = z0_w + nn * 128;
            for (int k = 0; k < 128; ++k) s += x0S[r][k] * zr[k];
            zS0[r][nn] = s;
        }
    }
    __syncthreads();

    // ---- z cached per-lane in C-frag layout (rows 4*lhi+j, col nc) ----
    float zc[4], krk[4];
#pragma unroll
    for (int j = 0; j < 4; ++j) {
        zc[j] = zS0[4 * lhi + j][nc];
        hbuf[4 * lhi + j][nc] = (_Float16)zc[j];
    }

    const float DT = 1.0f / 32.0f;

    // ---- bx streaming machinery (global loads; never drained in-loop) ----
    f32x4 s0a, s0b, s1a, s1b;
    auto stage = [&](int e) {
        const float pos = (float)e * 7.984375f;   // e*(511/64), exact
        const int i0 = (int)pos;
        const int i1 = (i0 < 511) ? i0 + 1 : 511;
        const float* base = past + (long)(b0 + lrow) * 16384;
        const float* p0 = base + i0 * 32 + koff;
        const float* p1 = base + i1 * 32 + koff;
        s0a = *(const f32x4*)p0; s0b = *(const f32x4*)(p0 + 4);
        s1a = *(const f32x4*)p1; s1b = *(const f32x4*)(p1 + 4);
    };
    auto blend = [&](int e) -> h8f16 {
        const float pos = (float)e * 7.984375f;
        const float w = pos - floorf(pos);
        h8f16 r;
#pragma unroll
        for (int j = 0; j < 4; ++j) {
            r[j]     = (_Float16)(s0a[j] + w * (s1a[j] - s0a[j]));
            r[4 + j] = (_Float16)(s0b[j] + w * (s1b[j] - s0b[j]));
        }
        return r;
    };

    // ---- phases ----
    const h2f16 one2 = {(_Float16)1.0f, (_Float16)1.0f};

    auto phaseA = [&](h8f16 bxc) {
        h8f16 xf[4];
#pragma unroll
        for (int ks = 0; ks < 4; ++ks)
            xf[ks] = *(const h8f16*)&hbuf[lrow][ks * 32 + koff];
        // LN stats via v_dot2_f32_f16 (2 independent accumulator chains each)
        float s0 = 0.f, s1 = 0.f, q0 = 0.f, q1 = 0.f;
#pragma unroll
        for (int ks = 0; ks < 4; ++ks) {
#pragma unroll
            for (int p = 0; p < 4; ++p) {
                const h2f16 x2 = {xf[ks][2 * p], xf[ks][2 * p + 1]};
                if (p & 1) {
                    s1 = __builtin_amdgcn_fdot2(x2, one2, s1, false);
                    q1 = __builtin_amdgcn_fdot2(x2, x2, q1, false);
                } else {
                    s0 = __builtin_amdgcn_fdot2(x2, one2, s0, false);
                    q0 = __builtin_amdgcn_fdot2(x2, x2, q0, false);
                }
            }
        }
        float s = s0 + s1, q = q0 + q1;
        s += __shfl_xor(s, 16); q += __shfl_xor(q, 16);
        s += __shfl_xor(s, 32); q += __shfl_xor(q, 32);
        const float mu  = s * (1.0f / 128.0f);
        const float var = q * (1.0f / 128.0f) - mu * mu;
        const float inv = 1.0f / sqrtf(var + 1e-5f);
        const _Float16 ih = (_Float16)inv;
        const _Float16 mh = (_Float16)(-mu * inv);
        h8f16 ip, mp;
#pragma unroll
        for (int j = 0; j < 8; ++j) { ip[j] = ih; mp[j] = mh; }
        f32x4 acc = {0, 0, 0, 0};
#pragma unroll
        for (int ks = 0; ks < 4; ++ks) {
            const h8f16 az = xf[ks] * ip + mp;   // packed f16 LN-apply (γ,β folded)
            acc = MFMA16(az, w1f[ks], acc);
        }
        acc = MFMA16(bxc, wcf, acc);
#pragma unroll
        for (int j = 0; j < 4; ++j)
            h1S[4 * lhi + j][nc] = (_Float16)silu_f(acc[j] + b1t);
    };
    auto phaseB = [&]() {
        f32x4 acc = {0, 0, 0, 0};
#pragma unroll
        for (int ks = 0; ks < 4; ++ks) {
            const h8f16 a = *(const h8f16*)&h1S[lrow][ks * 32 + koff];
            acc = MFMA16(a, w2f[ks], acc);
        }
#pragma unroll
        for (int j = 0; j < 4; ++j)
            h2S[4 * lhi + j][nc] = (_Float16)silu_f(acc[j] + b2r);
    };
    auto phaseC = [&]() -> f32x4 {
        f32x4 acc = {0, 0, 0, 0};
#pragma unroll
        for (int ks = 0; ks < 4; ++ks) {
            const h8f16 a = *(const h8f16*)&h2S[lrow][ks * 32 + koff];
            acc = MFMA16(a, w3f[ks], acc);
        }
#pragma unroll
        for (int j = 0; j < 4; ++j) acc[j] += b3r;
        return acc;
    };

    stage(0);
    h8f16 bxc = blend(0);
    __syncthreads();

#pragma unroll 1
    for (int st = 0; st < 32; ++st) {
        const int e1 = 2 * st + 1, e2 = 2 * st + 2;
        // ---- sub0: k1 ----
        phaseA(bxc);
        stage(e1);                                   // prefetch tile e1 (stays in flight)
        bar_lds();
        phaseB(); bar_lds();
        {
            const f32x4 k = phaseC();
#pragma unroll
            for (int j = 0; j < 4; ++j) {
                krk[j] = k[j];
                hbuf[4 * lhi + j][nc] = (_Float16)(zc[j] + 0.5f * DT * k[j]);
            }
        }
        bar_lds();
        // ---- sub1: k2 ----
        bxc = blend(e1);
        phaseA(bxc); bar_lds();
        phaseB(); bar_lds();
        {
            const f32x4 k = phaseC();
#pragma unroll
            for (int j = 0; j < 4; ++j) {
                krk[j] += 2.0f * k[j];
                hbuf[4 * lhi + j][nc] = (_Float16)(zc[j] + 0.5f * DT * k[j]);
            }
        }
        bar_lds();
        // ---- sub2: k3 ----
        phaseA(bxc);
        stage(e2);                                   // prefetch tile e2
        bar_lds();
        phaseB(); bar_lds();
        {
            const f32x4 k = phaseC();
#pragma unroll
            for (int j = 0; j < 4; ++j) {
                krk[j] += 2.0f * k[j];
                hbuf[4 * lhi + j][nc] = (_Float16)(zc[j] + DT * k[j]);
            }
        }
        bar_lds();
        // ---- sub3: k4 + z update ----
        bxc = blend(e2);
        phaseA(bxc); bar_lds();
        phaseB(); bar_lds();
        {
            const f32x4 k = phaseC();
#pragma unroll
            for (int j = 0; j < 4; ++j) {
                zc[j] += (DT / 6.0f) * (krk[j] + k[j]);
                hbuf[4 * lhi + j][nc] = (_Float16)zc[j];
            }
        }
        bar_lds();
    }

#pragma unroll
    for (int j = 0; j < 4; ++j)
        zbuf[(long)(b0 + 4 * lhi + j) * 128 + nc] = zc[j];
}

// ---------------------------------------------------------------------------
// hcat = [x_t flat (3072) | cond (128) | time-emb (128)] as f16
// ---------------------------------------------------------------------------
__global__ __launch_bounds__(256) void hcat_kernel(
    const float* __restrict__ x_t, const float* __restrict__ cond,
    const int* __restrict__ tvals, _Float16* __restrict__ hcat)
{
    const int gid = blockIdx.x * 256 + threadIdx.x;
    const int b  = gid / 416;
    const int j0 = (gid % 416) * 8;
    h8f16 v;
    if (j0 < 3072) {
        const float* s = x_t + (long)b * 3072 + j0;
#pragma unroll
        for (int j = 0; j < 8; ++j) v[j] = (_Float16)s[j];
    } else if (j0 < 3200) {
        const float* s = cond + (long)b * 128 + (j0 - 3072);
#pragma unroll
        for (int j = 0; j < 8; ++j) v[j] = (_Float16)s[j];
    } else {
        const float tv = (float)tvals[b];
#pragma unroll
        for (int j = 0; j < 8; ++j) {
            const int jj  = j0 - 3200 + j;
            const int idx = (jj < 64) ? jj : jj - 64;
            const float fr = expf(-9.210340371976184f * (float)idx * (1.0f / 63.0f));
            const float a  = tv * fr;
            v[j] = (_Float16)((jj < 64) ? sinf(a) : cosf(a));
        }
    }
    *(h8f16*)&hcat[(long)b * 3328 + j0] = v;
}

// ---------------------------------------------------------------------------
// Generic f16-MFMA GEMM: out(M,N) = [silu](A(M,K) @ W(N,K).T + bias)
// ---------------------------------------------------------------------------
template <bool SILU, bool OUT_F16>
__global__ __launch_bounds__(256) void gemm_f16(
    const _Float16* __restrict__ A, const float* __restrict__ W,
    const float* __restrict__ bias, void* __restrict__ out,
    int M, int N, int K)
{
    __shared__ _Float16 aS[64][40];
    __shared__ _Float16 wS[64][40];
    const int mb = blockIdx.x * 64, nb = blockIdx.y * 64;
    const int tid = threadIdx.x, lane = tid & 63, wq = tid >> 6;
    const int lrow = lane & 15, lhi = lane >> 4;
    f32x4 acc[4];
#pragma unroll
    for (int nt = 0; nt < 4; ++nt) acc[nt] = (f32x4){0, 0, 0, 0};

    const int sr = tid >> 2;
    const int sk = (tid & 3) * 8;

    for (int k0 = 0; k0 < K; k0 += 32) {
        {
            h8f16 v = *(const h8f16*)&A[(long)(mb + sr) * K + k0 + sk];
            *(h8f16*)&aS[sr][sk] = v;
        }
        {
            const float* s = &W[(long)(nb + sr) * K + k0 + sk];
            h8f16 v;
#pragma unroll
            for (int j = 0; j < 8; ++j) v[j] = (_Float16)s[j];
            *(h8f16*)&wS[sr][sk] = v;
        }
        __syncthreads();
        h8f16 a = *(const h8f16*)&aS[wq * 16 + lrow][lhi * 8];
#pragma unroll
        for (int nt = 0; nt < 4; ++nt) {
            h8f16 bfr = *(const h8f16*)&wS[nt * 16 + lrow][lhi * 8];
            acc[nt] = MFMA16(a, bfr, acc[nt]);
        }
        __syncthreads();
    }

#pragma unroll
    for (int nt = 0; nt < 4; ++nt) {
        const int cc = nb + nt * 16 + lrow;
        const float bv = bias[cc];
#pragma unroll
        for (int j = 0; j < 4; ++j) {
            const int rr = mb + wq * 16 + lhi * 4 + j;
            float v = acc[nt][j] + bv;
            if (SILU) v = silu_f(v);
            if (OUT_F16) ((_Float16*)out)[(long)rr * N + cc] = (_Float16)v;
            else         ((float*)out)[(long)rr * N + cc] = v;
        }
    }
}

// ---------------------------------------------------------------------------
extern "C" void kernel_launch(void* const* d_in, const int* in_sizes, int n_in,
                              void* d_out, int out_size, void* d_ws, size_t ws_size,
                              hipStream_t stream)
{
    const float* x_t     = (const float*)d_in[0];
    const float* past    = (const float*)d_in[1];
    const int*   tvals   = (const int*)d_in[2];
    const float* xproj_w = (const float*)d_in[3];
    const float* xproj_b = (const float*)d_in[4];
    const float* z0_w    = (const float*)d_in[5];
    const float* z0_b    = (const float*)d_in[6];
    const float* ln_g    = (const float*)d_in[7];
    const float* ln_b    = (const float*)d_in[8];
    const float* w1      = (const float*)d_in[9];
    const float* b1      = (const float*)d_in[10];
    const float* w2      = (const float*)d_in[11];
    const float* b2      = (const float*)d_in[12];
    const float* w3      = (const float*)d_in[13];
    const float* b3      = (const float*)d_in[14];
    const float* fw1     = (const float*)d_in[15];
    const float* fb1     = (const float*)d_in[16];
    const float* fw2     = (const float*)d_in[17];
    const float* fb2     = (const float*)d_in[18];
    const float* fw3     = (const float*)d_in[19];
    const float* fb3     = (const float*)d_in[20];

    char* ws = (char*)d_ws;
    float*     zbuf = (float*)ws;                               // 1 MB
    _Float16*  hcat = (_Float16*)(ws + (1 << 20));              // 13.63 MB
    _Float16*  h1   = (_Float16*)(ws + 15 * (1 << 20));         // 1 MB
    _Float16*  h2   = (_Float16*)(ws + 16 * (1 << 20));         // 1 MB

    ode_kernel<<<128, 512, 0, stream>>>(past, xproj_w, xproj_b, z0_w, z0_b,
                                        ln_g, ln_b, w1, b1, w2, b2, w3, b3, zbuf);

    hcat_kernel<<<(2048 * 416) / 256, 256, 0, stream>>>(x_t, zbuf, tvals, hcat);

    gemm_f16<true,  true ><<<dim3(32, 4),  256, 0, stream>>>(hcat, fw1, fb1, h1, 2048, 256, 3328);
    gemm_f16<true,  true ><<<dim3(32, 4),  256, 0, stream>>>(h1,   fw2, fb2, h2, 2048, 256, 256);
    gemm_f16<false, false><<<dim3(32, 48), 256, 0, stream>>>(h2,   fw3, fb3, d_out, 2048, 3072, 256);
}